// Round 8
// baseline (52.868 us; speedup 1.0000x reference)
//
#include <hip/hip_runtime.h>
#include <hip/hip_bf16.h>

#define NB 65536
#define ND 8
#define NE 16
#define NH 80
#define NF 9
#define NV 100000
#define NIN 160
#define WND 512   // samples per window; block = (window, domain)

typedef __attribute__((ext_vector_type(8))) short short8;    // 8 bf16 (4 VGPRs)
typedef __attribute__((ext_vector_type(4))) float float4v;   // MFMA acc

// ws layout in 4-byte units (weights only)
#define WS_W1BF   0        // bf16 fused W1, [d][n][k] linear: 8*80*160 ushort = 51200 u32
#define WS_B1F    51200    // 640 f32 [d][h]
#define WS_W2F    51840    // 640 f32 [d][h]
#define WS_B2F    52480    // 8 f32

__device__ inline unsigned int cvt2(float x, float y) {  // 2xf32 -> packed bf16 (RNE, HW cvt_pk)
  union { __hip_bfloat162 h; unsigned int u; } cv;
  cv.h = __float22bfloat162_rn(make_float2(x, y));
  return cv.u;
}

// k_fuse: star-merge the weights once (51200 u32 outputs).
__global__ void k_fuse(const float* __restrict__ sw1, const float* __restrict__ dw1,
                       const float* __restrict__ sb1, const float* __restrict__ db1,
                       const float* __restrict__ sw2, const float* __restrict__ dw2,
                       const float* __restrict__ sb2, const float* __restrict__ db2,
                       unsigned int* __restrict__ w1bf, float* __restrict__ wsf) {
  int t = blockIdx.x * 256 + threadIdx.x;
  if (t < ND * NH * (NIN / 2)) {          // one uint = 2 consecutive k of W1bf[d][n][k]
    int d = t / (NH * (NIN / 2));
    int r = t % (NH * (NIN / 2));
    int n = r / (NIN / 2);
    int k0 = (r % (NIN / 2)) * 2;
    float a = sw1[k0 * NH + n] * dw1[d * NIN * NH + k0 * NH + n];
    float b = sw1[(k0 + 1) * NH + n] * dw1[d * NIN * NH + (k0 + 1) * NH + n];
    w1bf[t] = cvt2(a, b);
  }
  if (t < ND * NH) {
    wsf[WS_B1F + t] = sb1[t % NH] + db1[t];
    wsf[WS_W2F + t] = sw2[t % NH] * dw2[t];
  }
  if (t < ND) wsf[WS_B2F + t] = sb2[0] + db2[t];
}

// k_main: block = (512-sample window, domain). Ballot-compact -> sid[] in LDS;
// A-fragments built DIRECTLY IN REGISTERS from the embedding gathers (each
// lane loads the 5 aligned 8-elem k-chunks of its own MFMA row; chunks 0-1
// come from the cached e_pid registers). No sA, no staging barrier. B = fused
// bf16 W1 in LDS (uint4-staged). Layer-2 fused in epilogue.
__global__ __launch_bounds__(256, 4) void k_main(
    const int* __restrict__ pid, const int* __restrict__ feats,
    const float* __restrict__ emb_pid, const float* __restrict__ emb_feats,
    const float* __restrict__ dl_w, const float* __restrict__ dl_b,
    const unsigned int* __restrict__ w1bf, const float* __restrict__ wsf,
    float* __restrict__ out) {
  const int d = blockIdx.x & 7;
  const int wnd = blockIdx.x >> 3;
  const int t = threadIdx.x, wave = t >> 6, lane = t & 63;

  __shared__ unsigned short sB[80][168];   // 26880 B (pitch 168: bank-safe)
  __shared__ int sid[WND];                 // 2048 B
  __shared__ int cnt[2][4];

  // 1) head of the dependent chain: pid window (coalesced)
  const int b0 = wnd * WND + t;
  const int b1 = b0 + 256;
  const int p0 = pid[b0];
  const int p1 = pid[b1];

  // 2) stage fused W1 into LDS, uint4-wide (independent stream, overlaps)
  {
    const uint4* __restrict__ wb4 = (const uint4*)(w1bf + d * (NH * (NIN / 2)));
    for (int i = t; i < NH * (NIN / 8); i += 256) {   // 1600 uint4
      int n = i / 20, c8 = i % 20;
      *(uint4*)&sB[n][c8 * 8] = wb4[i];
    }
  }

  const float dlb = dl_b[0];
  if (d == 0) {  // padding rows: e_pid row is zeros -> logits = dl_b exactly
    if (p0 == 0) out[b0] = dlb;
    if (p1 == 0) out[b1] = dlb;
  }

  // 3) ballot-rank compaction, two passes (t and t+256)
  unsigned long long m0 = __ballot(p0 == d + 1);
  unsigned long long m1 = __ballot(p1 == d + 1);
  if (lane == 0) { cnt[0][wave] = (int)__popcll(m0); cnt[1][wave] = (int)__popcll(m1); }
  const int r0 = (int)__popcll(m0 & ((1ull << lane) - 1ull));
  const int r1 = (int)__popcll(m1 & ((1ull << lane) - 1ull));

  // bucket-uniform hoists (register-only)
  float dlacc = dlb;
  unsigned int ep[8];
  {
    const float* __restrict__ row = emb_pid + (d + 1) * NE;
#pragma unroll
    for (int i = 0; i < NE; i += 2) {
      float x0 = fmaxf(row[i], 0.f), x1 = fmaxf(row[i + 1], 0.f);
      dlacc = fmaf(x0, dl_w[i], dlacc);
      dlacc = fmaf(x1, dl_w[i + 1], dlacc);
      ep[i >> 1] = cvt2(x0, x1);
    }
  }
  const float b2 = wsf[WS_B2F + d];
  float b1l[5], w2l[5];
#pragma unroll
  for (int nt = 0; nt < 5; ++nt) {
    b1l[nt] = wsf[WS_B1F + d * NH + nt * 16 + (lane & 15)];
    w2l[nt] = wsf[WS_W2F + d * NH + nt * 16 + (lane & 15)];
  }

  __syncthreads();   // cnt visible (and sB writes done)
  int base0 = 0, base1 = 0;
#pragma unroll
  for (int w = 0; w < 4; ++w)
    if (w < wave) { base0 += cnt[0][w]; base1 += cnt[1][w]; }
  const int tot0 = cnt[0][0] + cnt[0][1] + cnt[0][2] + cnt[0][3];
  const int c = tot0 + cnt[1][0] + cnt[1][1] + cnt[1][2] + cnt[1][3];
  if (p0 == d + 1) sid[base0 + r0] = b0;
  if (p1 == d + 1) sid[tot0 + base1 + r1] = b1;
  __syncthreads();   // sid ready

  const int q = lane >> 4;          // k-quad: A chunk m = q + 4*ks
  const int koff = q * 8;

  for (int g0 = 0; g0 < c; g0 += 64) {
    const int srow = g0 + wave * 16 + (lane & 15);
    const int bb = sid[srow < c ? srow : 0];

    // feat element-offsets for this lane's 5 chunks (m<2 served from ep regs)
    int off[5];
#pragma unroll
    for (int ks = 0; ks < 5; ++ks) {
      int m = q + 4 * ks;
      if (m >= 2) {
        int f = (m - 2) >> 1;
        off[ks] = (f * (NV + 1) + feats[bb * NF + f]) * NE + ((m - 2) & 1) * 8;
      }
    }
    // issue all gathers back-to-back (independent)
    float4 lo[5], hi[5];
#pragma unroll
    for (int ks = 0; ks < 5; ++ks) {
      int m = q + 4 * ks;
      if (m >= 2) {
        const float4* __restrict__ src = (const float4*)(emb_feats + (size_t)off[ks]);
        lo[ks] = src[0];
        hi[ks] = src[1];
      }
    }
    // convert to A-fragments in registers
    unsigned int e0 = q ? ep[4] : ep[0];
    unsigned int e1 = q ? ep[5] : ep[1];
    unsigned int e2 = q ? ep[6] : ep[2];
    unsigned int e3 = q ? ep[7] : ep[3];
    short8 af[5];
#pragma unroll
    for (int ks = 0; ks < 5; ++ks) {
      int m = q + 4 * ks;
      union { unsigned int u[4]; short8 s; } cv;
      if (m < 2) {
        cv.u[0] = e0; cv.u[1] = e1; cv.u[2] = e2; cv.u[3] = e3;
      } else {
        cv.u[0] = cvt2(fmaxf(lo[ks].x, 0.f), fmaxf(lo[ks].y, 0.f));
        cv.u[1] = cvt2(fmaxf(lo[ks].z, 0.f), fmaxf(lo[ks].w, 0.f));
        cv.u[2] = cvt2(fmaxf(hi[ks].x, 0.f), fmaxf(hi[ks].y, 0.f));
        cv.u[3] = cvt2(fmaxf(hi[ks].z, 0.f), fmaxf(hi[ks].w, 0.f));
      }
      af[ks] = cv.s;
    }

    // MFMA: A from regs; B lane l -> col l&15, k = ks*32 + koff
    float4v acc[5];
#pragma unroll
    for (int nt = 0; nt < 5; ++nt)
      acc[nt] = (float4v){b1l[nt], b1l[nt], b1l[nt], b1l[nt]};
#pragma unroll
    for (int ks = 0; ks < 5; ++ks) {
#pragma unroll
      for (int nt = 0; nt < 5; ++nt) {
        short8 bf = *(const short8*)&sB[nt * 16 + (lane & 15)][ks * 32 + koff];
        acc[nt] = __builtin_amdgcn_mfma_f32_16x16x32_bf16(af[ks], bf, acc[nt], 0, 0, 0);
      }
    }

    // layer 2: relu(h) . w2, reduce across the 16-lane n-groups
    float pr[4];
#pragma unroll
    for (int r = 0; r < 4; ++r) {
      float a2 = 0.f;
#pragma unroll
      for (int nt = 0; nt < 5; ++nt) a2 = fmaf(fmaxf(acc[nt][r], 0.f), w2l[nt], a2);
      pr[r] = a2;
    }
#pragma unroll
    for (int r = 0; r < 4; ++r) {
      pr[r] += __shfl_xor(pr[r], 1);
      pr[r] += __shfl_xor(pr[r], 2);
      pr[r] += __shfl_xor(pr[r], 4);
      pr[r] += __shfl_xor(pr[r], 8);
    }
    if ((lane & 15) == 0) {
      int srow2 = wave * 16 + (lane >> 4) * 4;
#pragma unroll
      for (int r = 0; r < 4; ++r) {
        int kk = g0 + srow2 + r;
        if (kk < c) out[sid[kk]] = pr[r] + b2 + dlacc;
      }
    }
  }
}

extern "C" void kernel_launch(void* const* d_in, const int* in_sizes, int n_in,
                              void* d_out, int out_size, void* d_ws, size_t ws_size,
                              hipStream_t stream) {
  const int*   pid      = (const int*)d_in[0];
  const int*   feats    = (const int*)d_in[1];
  const float* emb_pid  = (const float*)d_in[2];
  const float* emb_f    = (const float*)d_in[3];
  const float* sw1      = (const float*)d_in[4];
  const float* dw1      = (const float*)d_in[5];
  const float* sb1      = (const float*)d_in[6];
  const float* db1      = (const float*)d_in[7];
  const float* sw2      = (const float*)d_in[8];
  const float* dw2      = (const float*)d_in[9];
  const float* sb2      = (const float*)d_in[10];
  const float* db2      = (const float*)d_in[11];
  const float* dl_w     = (const float*)d_in[12];
  const float* dl_b     = (const float*)d_in[13];
  float* out = (float*)d_out;
  float* wsf = (float*)d_ws;
  unsigned int* w1bf = (unsigned int*)d_ws;

  k_fuse<<<(ND * NH * (NIN / 2) + 255) / 256, 256, 0, stream>>>(
      sw1, dw1, sb1, db1, sw2, dw2, sb2, db2, w1bf, wsf);
  k_main<<<(NB / WND) * ND, 256, 0, stream>>>(pid, feats, emb_pid, emb_f,
                                              dl_w, dl_b, w1bf, wsf, out);
}

// Round 9
// 26.873 us; speedup vs baseline: 1.9673x; 1.9673x over previous
//
#include <hip/hip_runtime.h>
#include <hip/hip_bf16.h>

#define NB 65536
#define ND 8
#define NE 16
#define NH 80
#define NF 9
#define NV 100000
#define NIN 160
#define WND 1024          // samples per window
#define NWND (NB / WND)   // 64 windows; grid = 64*8 = 512 = 2 blocks/CU

typedef __attribute__((ext_vector_type(8))) short short8;    // 8 bf16 (4 VGPRs)
typedef __attribute__((ext_vector_type(4))) float float4v;   // MFMA acc

__device__ inline unsigned short f2bf(float x) {   // RNE f32->bf16 (scalar)
  unsigned int u = __float_as_uint(x);
  return (unsigned short)((u + 0x7fffu + ((u >> 16) & 1u)) >> 16);
}
__device__ inline unsigned int cvt2(float x, float y) {  // HW v_cvt_pk path
  union { __hip_bfloat162 h; unsigned int u; } cv;
  cv.h = __float22bfloat162_rn(make_float2(x, y));
  return cv.u;
}

// Single fused kernel. Block = (1024-sample window, domain), 8 waves.
// Phase 1 (overlapped): pid window load | in-block W1 star-merge into LDS
// (B-fragment layout, conflict-free) | bucket-uniform hoists.
// Phase 2: ballot-rank compaction -> sOrig[] (no atomics, no metadata).
// Phase 3: per 128-row tile: 4-thread/sample coalesced gathers -> relu/bf16
// -> sA -> MFMA 16x16x32 -> fused layer-2 epilogue -> out.
__global__ __launch_bounds__(512, 4) void k_main(
    const int* __restrict__ pid, const int* __restrict__ feats,
    const float* __restrict__ emb_pid, const float* __restrict__ emb_feats,
    const float* __restrict__ sw1, const float* __restrict__ dw1,
    const float* __restrict__ sb1, const float* __restrict__ db1,
    const float* __restrict__ sw2, const float* __restrict__ dw2,
    const float* __restrict__ sb2, const float* __restrict__ db2,
    const float* __restrict__ dl_w, const float* __restrict__ dl_b,
    float* __restrict__ out) {
  const int d = blockIdx.x >> 6;    // same-window blocks are stride-64 apart
  const int wnd = blockIdx.x & 63;  // -> same XCD (round-robin dispatch), L2 reuse
  const int t = threadIdx.x, wave = t >> 6, lane = t & 63;

  __shared__ unsigned short sA[128][168];         // 43008 B (pitch 168: 2-way banks)
  __shared__ unsigned short sBF[5][5][4][16][8];  // 25600 B  [nt][ks][q][col][e]
  __shared__ int sOrig[WND];                      // 4096 B
  __shared__ int cnt0[8], cnt1[8];

  // ---- 1a) chain head: pid window (coalesced) ----
  const int b0 = wnd * WND + t;
  const int b1 = b0 + 512;
  const int p0 = pid[b0];
  const int p1 = pid[b1];

  // ---- 1b) star-merge W1 into B-fragment layout (independent stream) ----
  for (int i = t; i < NIN * NH; i += 512) {   // 25 per thread
    int k = i / NH, n = i % NH;               // sw1/dw1 are [k][n] -> flat i
    float w = sw1[i] * dw1[d * (NIN * NH) + i];
    sBF[n >> 4][k >> 5][(k >> 3) & 3][n & 15][k & 7] = f2bf(w);
  }

  // ---- 1c) bucket-uniform hoists (register-only) ----
  const float dlb = dl_b[0];
  float dlacc = dlb;
  unsigned int ep[8];
  {
    const float* __restrict__ row = emb_pid + (d + 1) * NE;
#pragma unroll
    for (int i = 0; i < NE; i += 2) {
      float x0 = fmaxf(row[i], 0.f), x1 = fmaxf(row[i + 1], 0.f);
      dlacc = fmaf(x0, dl_w[i], dlacc);
      dlacc = fmaf(x1, dl_w[i + 1], dlacc);
      ep[i >> 1] = cvt2(x0, x1);
    }
  }
  float b1l[5], w2l[5];
#pragma unroll
  for (int nt = 0; nt < 5; ++nt) {
    int h = nt * 16 + (lane & 15);
    b1l[nt] = sb1[h] + db1[d * NH + h];
    w2l[nt] = sw2[h] * dw2[d * NH + h];
  }
  const float b2 = sb2[0] + db2[d];

  if (d == 0) {  // padding rows: e_pid row is zeros -> logits = dl_b exactly
    if (p0 == 0) out[b0] = dlb;
    if (p1 == 0) out[b1] = dlb;
  }

  // ---- 2) ballot-rank compaction (two passes: t, t+512) ----
  unsigned long long m0 = __ballot(p0 == d + 1);
  unsigned long long m1 = __ballot(p1 == d + 1);
  if (lane == 0) { cnt0[wave] = (int)__popcll(m0); cnt1[wave] = (int)__popcll(m1); }
  const unsigned long long lt = (1ull << lane) - 1ull;
  const int r0 = (int)__popcll(m0 & lt);
  const int r1 = (int)__popcll(m1 & lt);
  __syncthreads();   // cnt + sBF visible
  int base0 = 0, tot0 = 0, base1 = 0, tot1 = 0;
#pragma unroll
  for (int w = 0; w < 8; ++w) {
    if (w < wave) { base0 += cnt0[w]; base1 += cnt1[w]; }
    tot0 += cnt0[w]; tot1 += cnt1[w];
  }
  const int c = tot0 + tot1;
  if (p0 == d + 1) sOrig[base0 + r0] = b0;
  if (p1 == d + 1) sOrig[tot0 + base1 + r1] = b1;
  __syncthreads();   // sOrig ready

  // ---- 3) 128-row tiles ----
  for (int g0 = 0; g0 < c; g0 += 128) {
    const int s = t >> 2, q = t & 3;      // 4 threads per sample
    int ss = g0 + s; if (ss >= c) ss = c - 1;
    const int bb = sOrig[ss];

    int idx[NF];
#pragma unroll
    for (int f = 0; f < NF; ++f) idx[f] = feats[bb * NF + f];
    float4 vv[NF];
#pragma unroll
    for (int f = 0; f < NF; ++f)
      vv[f] = *(const float4*)(emb_feats +
                               (size_t)((f * (NV + 1) + idx[f]) * NE + q * 4));
    if (q < 2) {  // e_pid columns 0..15 (bucket-uniform)
      unsigned int* dst = (unsigned int*)&sA[s][0];
#pragma unroll
      for (int j = 0; j < 4; ++j) dst[q * 4 + j] = ep[q * 4 + j];
    }
#pragma unroll
    for (int f = 0; f < NF; ++f) {
      unsigned int lo = cvt2(fmaxf(vv[f].x, 0.f), fmaxf(vv[f].y, 0.f));
      unsigned int hi = cvt2(fmaxf(vv[f].z, 0.f), fmaxf(vv[f].w, 0.f));
      unsigned int* dst = (unsigned int*)&sA[s][16 + f * 16];
      dst[q * 2] = lo;
      dst[q * 2 + 1] = hi;
    }
    __syncthreads();

    // MFMA: A lane l -> row l&15 (of this wave's 16), k = (l>>4)*8+e
    float4v acc[5];
#pragma unroll
    for (int nt = 0; nt < 5; ++nt)
      acc[nt] = (float4v){b1l[nt], b1l[nt], b1l[nt], b1l[nt]};
    const int arow = wave * 16 + (lane & 15);
    const int koff = (lane >> 4) * 8;
#pragma unroll
    for (int ks = 0; ks < 5; ++ks) {
      short8 af = *(const short8*)&sA[arow][ks * 32 + koff];
#pragma unroll
      for (int nt = 0; nt < 5; ++nt) {
        short8 bf = *(const short8*)&sBF[nt][ks][lane >> 4][lane & 15][0];
        acc[nt] = __builtin_amdgcn_mfma_f32_16x16x32_bf16(af, bf, acc[nt], 0, 0, 0);
      }
    }

    // layer 2: relu(h) . w2, reduce across each 16-lane col-group
    float pr[4];
#pragma unroll
    for (int r = 0; r < 4; ++r) {
      float a2 = 0.f;
#pragma unroll
      for (int nt = 0; nt < 5; ++nt) a2 = fmaf(fmaxf(acc[nt][r], 0.f), w2l[nt], a2);
      pr[r] = a2;
    }
#pragma unroll
    for (int r = 0; r < 4; ++r) {
      pr[r] += __shfl_xor(pr[r], 1);
      pr[r] += __shfl_xor(pr[r], 2);
      pr[r] += __shfl_xor(pr[r], 4);
      pr[r] += __shfl_xor(pr[r], 8);
    }
    if ((lane & 15) == 0) {
      int srow2 = wave * 16 + (lane >> 4) * 4;
#pragma unroll
      for (int r = 0; r < 4; ++r) {
        int kk = g0 + srow2 + r;
        if (kk < c) out[sOrig[kk]] = pr[r] + b2 + dlacc;
      }
    }
    if (g0 + 128 < c) __syncthreads();   // only if another tile follows
  }
}

extern "C" void kernel_launch(void* const* d_in, const int* in_sizes, int n_in,
                              void* d_out, int out_size, void* d_ws, size_t ws_size,
                              hipStream_t stream) {
  const int*   pid      = (const int*)d_in[0];
  const int*   feats    = (const int*)d_in[1];
  const float* emb_pid  = (const float*)d_in[2];
  const float* emb_f    = (const float*)d_in[3];
  const float* sw1      = (const float*)d_in[4];
  const float* dw1      = (const float*)d_in[5];
  const float* sb1      = (const float*)d_in[6];
  const float* db1      = (const float*)d_in[7];
  const float* sw2      = (const float*)d_in[8];
  const float* dw2      = (const float*)d_in[9];
  const float* sb2      = (const float*)d_in[10];
  const float* db2      = (const float*)d_in[11];
  const float* dl_w     = (const float*)d_in[12];
  const float* dl_b     = (const float*)d_in[13];
  float* out = (float*)d_out;
  (void)d_ws; (void)ws_size;

  k_main<<<NWND * ND, 512, 0, stream>>>(pid, feats, emb_pid, emb_f, sw1, dw1,
                                        sb1, db1, sw2, dw2, sb2, db2, dl_w,
                                        dl_b, out);
}

// Round 10
// 24.600 us; speedup vs baseline: 2.1491x; 1.0924x over previous
//
#include <hip/hip_runtime.h>
#include <hip/hip_bf16.h>

#define NB 65536
#define ND 8
#define NE 16
#define NH 80
#define NF 9
#define NV 100000
#define NIN 160
#define WND 1024          // samples per window
#define NWND (NB / WND)   // 64 windows; grid = 64*8 = 512 = 2 blocks/CU

typedef __attribute__((ext_vector_type(8))) short short8;    // 8 bf16 (4 VGPRs)
typedef __attribute__((ext_vector_type(4))) float float4v;   // MFMA acc

__device__ inline unsigned short f2bf(float x) {   // RNE f32->bf16 (scalar)
  unsigned int u = __float_as_uint(x);
  return (unsigned short)((u + 0x7fffu + ((u >> 16) & 1u)) >> 16);
}
__device__ inline unsigned int cvt2(float x, float y) {  // HW v_cvt_pk path
  union { __hip_bfloat162 h; unsigned int u; } cv;
  cv.h = __float22bfloat162_rn(make_float2(x, y));
  return cv.u;
}

// Single fused kernel, producer/consumer wave split.
// Block = (1024-sample window, domain), 8 waves:
//   waves 4-7: gather-producers (4 thr/sample, 64 samples/volley, double-buffered sA)
//   waves 0-3: MFMA-consumers (16-row strip each, fused layer-2 epilogue)
// stage(k+1) overlaps MFMA(k) -> gathers stay in flight most of the block's life.
__global__ __launch_bounds__(512, 4) void k_main(
    const int* __restrict__ pid, const int* __restrict__ feats,
    const float* __restrict__ emb_pid, const float* __restrict__ emb_feats,
    const float* __restrict__ sw1, const float* __restrict__ dw1,
    const float* __restrict__ sb1, const float* __restrict__ db1,
    const float* __restrict__ sw2, const float* __restrict__ dw2,
    const float* __restrict__ sb2, const float* __restrict__ db2,
    const float* __restrict__ dl_w, const float* __restrict__ dl_b,
    float* __restrict__ out) {
  const int d = blockIdx.x >> 6;    // same-window blocks stride-64 apart
  const int wnd = blockIdx.x & 63;
  const int t = threadIdx.x, wave = t >> 6, lane = t & 63;

  __shared__ unsigned short sA[2][64][168];       // 43008 B, double-buffered tile
  __shared__ unsigned short sBF[5][5][4][16][8];  // 25600 B  [nt][ks][q][col][e]
  __shared__ int sOrig[WND];                      // 4096 B
  __shared__ int cnt0[8], cnt1[8];

  // ---- phase 1: chain head (pid) + in-block W1 star-merge + hoists ----
  const int b0 = wnd * WND + t;
  const int b1 = b0 + 512;
  const int p0 = pid[b0];
  const int p1 = pid[b1];

  for (int i = t; i < NIN * NH; i += 512) {   // 25 per thread
    int k = i / NH, n = i % NH;               // sw1/dw1 are [k][n] -> flat i
    float w = sw1[i] * dw1[d * (NIN * NH) + i];
    sBF[n >> 4][k >> 5][(k >> 3) & 3][n & 15][k & 7] = f2bf(w);
  }

  const float dlb = dl_b[0];
  float dlacc = dlb;
  unsigned int ep[8];
  {
    const float* __restrict__ row = emb_pid + (d + 1) * NE;
#pragma unroll
    for (int i = 0; i < NE; i += 2) {
      float x0 = fmaxf(row[i], 0.f), x1 = fmaxf(row[i + 1], 0.f);
      dlacc = fmaf(x0, dl_w[i], dlacc);
      dlacc = fmaf(x1, dl_w[i + 1], dlacc);
      ep[i >> 1] = cvt2(x0, x1);
    }
  }
  float b1l[5], w2l[5];
#pragma unroll
  for (int nt = 0; nt < 5; ++nt) {
    int h = nt * 16 + (lane & 15);
    b1l[nt] = sb1[h] + db1[d * NH + h];
    w2l[nt] = sw2[h] * dw2[d * NH + h];
  }
  const float b2 = sb2[0] + db2[d];

  if (d == 0) {  // padding rows: e_pid row is zeros -> logits = dl_b exactly
    if (p0 == 0) out[b0] = dlb;
    if (p1 == 0) out[b1] = dlb;
  }

  // ---- phase 2: ballot-rank compaction ----
  unsigned long long m0 = __ballot(p0 == d + 1);
  unsigned long long m1 = __ballot(p1 == d + 1);
  if (lane == 0) { cnt0[wave] = (int)__popcll(m0); cnt1[wave] = (int)__popcll(m1); }
  const unsigned long long lt = (1ull << lane) - 1ull;
  const int r0 = (int)__popcll(m0 & lt);
  const int r1 = (int)__popcll(m1 & lt);
  __syncthreads();   // cnt + sBF visible
  int base0 = 0, tot0 = 0, base1 = 0;
#pragma unroll
  for (int w = 0; w < 8; ++w) {
    if (w < wave) { base0 += cnt0[w]; base1 += cnt1[w]; }
    tot0 += cnt0[w];
  }
  int c = tot0;
#pragma unroll
  for (int w = 0; w < 8; ++w) c += cnt1[w];
  if (p0 == d + 1) sOrig[base0 + r0] = b0;
  if (p1 == d + 1) sOrig[tot0 + base1 + r1] = b1;
  __syncthreads();   // sOrig ready

  if (c == 0) return;                 // block-uniform
  const int ntiles = (c + 63) >> 6;
  const bool prod = wave >= 4;

  // producer volley: stage 64 samples into sA[buf] (4 threads/sample)
  auto stage = [&](int buf, int g0) {
    const int s = (t & 255) >> 2, q = t & 3;
    int ss = g0 + s; if (ss >= c) ss = c - 1;
    const int bb = sOrig[ss];
    int idx[NF];
#pragma unroll
    for (int f = 0; f < NF; ++f) idx[f] = feats[bb * NF + f];
    float4 vv[NF];
#pragma unroll
    for (int f = 0; f < NF; ++f)
      vv[f] = *(const float4*)(emb_feats +
                               (size_t)((f * (NV + 1) + idx[f]) * NE + q * 4));
    if (q < 2) {  // e_pid columns 0..15 (bucket-uniform)
      unsigned int* dst = (unsigned int*)&sA[buf][s][0];
#pragma unroll
      for (int j = 0; j < 4; ++j) dst[q * 4 + j] = ep[q * 4 + j];
    }
#pragma unroll
    for (int f = 0; f < NF; ++f) {
      unsigned int lo = cvt2(fmaxf(vv[f].x, 0.f), fmaxf(vv[f].y, 0.f));
      unsigned int hi = cvt2(fmaxf(vv[f].z, 0.f), fmaxf(vv[f].w, 0.f));
      unsigned int* dst = (unsigned int*)&sA[buf][s][16 + f * 16];
      dst[q * 2] = lo;
      dst[q * 2 + 1] = hi;
    }
  };

  if (prod) stage(0, 0);
  __syncthreads();

  for (int k = 0; k < ntiles; ++k) {
    const int g0 = k * 64;
    if (prod) {
      if (k + 1 < ntiles) stage((k + 1) & 1, g0 + 64);
    } else if (g0 + wave * 16 < c) {   // strip-skip for the ragged tail
      const int buf = k & 1;
      float4v acc[5];
#pragma unroll
      for (int nt = 0; nt < 5; ++nt)
        acc[nt] = (float4v){b1l[nt], b1l[nt], b1l[nt], b1l[nt]};
      const int arow = wave * 16 + (lane & 15);
      const int koff = (lane >> 4) * 8;
#pragma unroll
      for (int ks = 0; ks < 5; ++ks) {
        short8 af = *(const short8*)&sA[buf][arow][ks * 32 + koff];
#pragma unroll
        for (int nt = 0; nt < 5; ++nt) {
          short8 bf = *(const short8*)&sBF[nt][ks][lane >> 4][lane & 15][0];
          acc[nt] = __builtin_amdgcn_mfma_f32_16x16x32_bf16(af, bf, acc[nt], 0, 0, 0);
        }
      }
      float pr[4];
#pragma unroll
      for (int r = 0; r < 4; ++r) {
        float a2 = 0.f;
#pragma unroll
        for (int nt = 0; nt < 5; ++nt) a2 = fmaf(fmaxf(acc[nt][r], 0.f), w2l[nt], a2);
        pr[r] = a2;
      }
#pragma unroll
      for (int r = 0; r < 4; ++r) {
        pr[r] += __shfl_xor(pr[r], 1);
        pr[r] += __shfl_xor(pr[r], 2);
        pr[r] += __shfl_xor(pr[r], 4);
        pr[r] += __shfl_xor(pr[r], 8);
      }
      if ((lane & 15) == 0) {
        int srow2 = wave * 16 + (lane >> 4) * 4;
#pragma unroll
        for (int r = 0; r < 4; ++r) {
          int kk = g0 + srow2 + r;
          if (kk < c) out[sOrig[kk]] = pr[r] + b2 + dlacc;
        }
      }
    }
    __syncthreads();   // stage(k+1) done AND consumers done with sA[k&1]
  }
}

extern "C" void kernel_launch(void* const* d_in, const int* in_sizes, int n_in,
                              void* d_out, int out_size, void* d_ws, size_t ws_size,
                              hipStream_t stream) {
  const int*   pid      = (const int*)d_in[0];
  const int*   feats    = (const int*)d_in[1];
  const float* emb_pid  = (const float*)d_in[2];
  const float* emb_f    = (const float*)d_in[3];
  const float* sw1      = (const float*)d_in[4];
  const float* dw1      = (const float*)d_in[5];
  const float* sb1      = (const float*)d_in[6];
  const float* db1      = (const float*)d_in[7];
  const float* sw2      = (const float*)d_in[8];
  const float* dw2      = (const float*)d_in[9];
  const float* sb2      = (const float*)d_in[10];
  const float* db2      = (const float*)d_in[11];
  const float* dl_w     = (const float*)d_in[12];
  const float* dl_b     = (const float*)d_in[13];
  float* out = (float*)d_out;
  (void)d_ws; (void)ws_size;

  k_main<<<NWND * ND, 512, 0, stream>>>(pid, feats, emb_pid, emb_f, sw1, dw1,
                                        sb1, db1, sw2, dw2, sb2, db2, dl_w,
                                        dl_b, out);
}

// Round 11
// 24.320 us; speedup vs baseline: 2.1738x; 1.0115x over previous
//
#include <hip/hip_runtime.h>
#include <hip/hip_bf16.h>

#define NB 65536
#define ND 8
#define NE 16
#define NH 80
#define NF 9
#define NV 100000
#define NIN 160
#define WND 2048          // samples per window
#define NWND (NB / WND)   // 32 windows; grid = 32*8 = 256 = 1 block/CU

typedef __attribute__((ext_vector_type(8))) short short8;    // 8 bf16 (4 VGPRs)
typedef __attribute__((ext_vector_type(4))) float float4v;   // MFMA acc

__device__ inline unsigned short f2bf(float x) {   // RNE f32->bf16 (scalar)
  unsigned int u = __float_as_uint(x);
  return (unsigned short)((u + 0x7fffu + ((u >> 16) & 1u)) >> 16);
}
__device__ inline unsigned int cvt2(float x, float y) {  // HW v_cvt_pk path
  union { __hip_bfloat162 h; unsigned int u; } cv;
  cv.h = __float22bfloat162_rn(make_float2(x, y));
  return cv.u;
}

// Single fused kernel, deep-pipelined producer/consumer.
// Block = (2048-sample window, domain), 8 waves, 1 block/CU.
//   prologue: ALL 8 waves stage volleys 0+1 (two 64-row tiles, full issue width)
//   loop:     waves 4-7 stage volley k+2 (triple-buffered sA) | waves 0-3 MFMA(k)
// Setup (pid, in-block W1 star-merge, ballot-compact) amortized over ~4 volleys.
__global__ __launch_bounds__(512, 2) void k_main(
    const int* __restrict__ pid, const int* __restrict__ feats,
    const float* __restrict__ emb_pid, const float* __restrict__ emb_feats,
    const float* __restrict__ sw1, const float* __restrict__ dw1,
    const float* __restrict__ sb1, const float* __restrict__ db1,
    const float* __restrict__ sw2, const float* __restrict__ dw2,
    const float* __restrict__ sb2, const float* __restrict__ db2,
    const float* __restrict__ dl_w, const float* __restrict__ dl_b,
    float* __restrict__ out) {
  const int d = blockIdx.x >> 5;    // same-window blocks stride-32 apart -> same XCD
  const int wnd = blockIdx.x & 31;
  const int t = threadIdx.x, wave = t >> 6, lane = t & 63;

  __shared__ unsigned short sA[3][64][168];       // 64512 B, triple-buffered tiles
  __shared__ unsigned short sBF[5][5][4][16][8];  // 25600 B  [nt][ks][q][col][e]
  __shared__ int sOrig[WND];                      // 8192 B
  __shared__ int scnt[4][8];

  // ---- phase 1: chain head (pid, 4 passes) + W1 star-merge + hoists ----
  const int bbase = wnd * WND + t;
  int pp[4];
#pragma unroll
  for (int pass = 0; pass < 4; ++pass) pp[pass] = pid[bbase + pass * 512];

  for (int i = t; i < NIN * NH; i += 512) {   // 25 per thread, coalesced
    int k = i / NH, n = i % NH;               // sw1/dw1 are [k][n] -> flat i
    float w = sw1[i] * dw1[d * (NIN * NH) + i];
    sBF[n >> 4][k >> 5][(k >> 3) & 3][n & 15][k & 7] = f2bf(w);
  }

  const float dlb = dl_b[0];
  float dlacc = dlb;
  unsigned int ep[8];
  {
    const float* __restrict__ row = emb_pid + (d + 1) * NE;
#pragma unroll
    for (int i = 0; i < NE; i += 2) {
      float x0 = fmaxf(row[i], 0.f), x1 = fmaxf(row[i + 1], 0.f);
      dlacc = fmaf(x0, dl_w[i], dlacc);
      dlacc = fmaf(x1, dl_w[i + 1], dlacc);
      ep[i >> 1] = cvt2(x0, x1);
    }
  }
  float b1l[5], w2l[5];
#pragma unroll
  for (int nt = 0; nt < 5; ++nt) {
    int h = nt * 16 + (lane & 15);
    b1l[nt] = sb1[h] + db1[d * NH + h];
    w2l[nt] = sw2[h] * dw2[d * NH + h];
  }
  const float b2 = sb2[0] + db2[d];

  if (d == 0) {  // padding rows: e_pid row is zeros -> logits = dl_b exactly
#pragma unroll
    for (int pass = 0; pass < 4; ++pass)
      if (pp[pass] == 0) out[bbase + pass * 512] = dlb;
  }

  // ---- phase 2: ballot-rank compaction, 4 passes ----
  const unsigned long long lt = (1ull << lane) - 1ull;
  int rr[4];
#pragma unroll
  for (int pass = 0; pass < 4; ++pass) {
    unsigned long long m = __ballot(pp[pass] == d + 1);
    if (lane == 0) scnt[pass][wave] = (int)__popcll(m);
    rr[pass] = (int)__popcll(m & lt);
  }
  __syncthreads();   // scnt + sBF visible
  int pbase[4], run = 0;
#pragma unroll
  for (int pass = 0; pass < 4; ++pass) {
    int bw = 0, tt = 0;
#pragma unroll
    for (int w = 0; w < 8; ++w) {
      int v = scnt[pass][w];
      if (w < wave) bw += v;
      tt += v;
    }
    pbase[pass] = run + bw;
    run += tt;
  }
  const int c = run;
#pragma unroll
  for (int pass = 0; pass < 4; ++pass)
    if (pp[pass] == d + 1) sOrig[pbase[pass] + rr[pass]] = bbase + pass * 512;
  __syncthreads();   // sOrig ready

  if (c == 0) return;                 // block-uniform
  const int ntiles = (c + 63) >> 6;

  // stage one 64-sample volley into sA[buf]; t256 in [0,256), 4 threads/sample.
  // feats dedup: each lane loads 2-3 indices, group shares via shfl.
  auto stage = [&](int buf, int g0, int t256) {
    const int s = t256 >> 2, q = t256 & 3;
    int ss = g0 + s; if (ss >= c) ss = c - 1;
    const int bb = sOrig[ss];
    const int fb = bb * NF;
    int ia = feats[fb + q];
    int ib = feats[fb + 4 + q];
    int ic = (q == 0) ? feats[fb + 8] : 0;
    const int gl = lane & ~3;
    int idx[NF];
#pragma unroll
    for (int f = 0; f < 4; ++f) idx[f] = __shfl(ia, gl + f);
#pragma unroll
    for (int f = 0; f < 4; ++f) idx[4 + f] = __shfl(ib, gl + f);
    idx[8] = __shfl(ic, gl);
    float4 vv[NF];
#pragma unroll
    for (int f = 0; f < NF; ++f)
      vv[f] = *(const float4*)(emb_feats +
                               (size_t)((f * (NV + 1) + idx[f]) * NE + q * 4));
    if (q < 2) {  // e_pid columns 0..15 (bucket-uniform)
      unsigned int* dst = (unsigned int*)&sA[buf][s][0];
#pragma unroll
      for (int j = 0; j < 4; ++j) dst[q * 4 + j] = ep[q * 4 + j];
    }
#pragma unroll
    for (int f = 0; f < NF; ++f) {
      uint2 w;
      w.x = cvt2(fmaxf(vv[f].x, 0.f), fmaxf(vv[f].y, 0.f));
      w.y = cvt2(fmaxf(vv[f].z, 0.f), fmaxf(vv[f].w, 0.f));
      *(uint2*)((unsigned int*)&sA[buf][s][16 + f * 16] + q * 2) = w;
    }
  };

  // ---- prologue: full-width double stage (volleys 0 and 1) ----
  if (wave < 4) stage(0, 0, t);
  else if (ntiles > 1) stage(1, 64, t - 256);
  __syncthreads();

  // ---- steady state: stage(k+2) || MFMA(k) ----
  for (int k = 0; k < ntiles; ++k) {
    if (wave >= 4) {
      if (k + 2 < ntiles) stage((k + 2) % 3, (k + 2) * 64, t - 256);
    } else {
      const int g0 = k * 64;
      if (g0 + wave * 16 < c) {   // strip-skip for the ragged tail
        const int buf = k % 3;
        float4v acc[5];
#pragma unroll
        for (int nt = 0; nt < 5; ++nt)
          acc[nt] = (float4v){b1l[nt], b1l[nt], b1l[nt], b1l[nt]};
        const int arow = wave * 16 + (lane & 15);
        const int koff = (lane >> 4) * 8;
#pragma unroll
        for (int ks = 0; ks < 5; ++ks) {
          short8 af = *(const short8*)&sA[buf][arow][ks * 32 + koff];
#pragma unroll
          for (int nt = 0; nt < 5; ++nt) {
            short8 bf = *(const short8*)&sBF[nt][ks][lane >> 4][lane & 15][0];
            acc[nt] = __builtin_amdgcn_mfma_f32_16x16x32_bf16(af, bf, acc[nt], 0, 0, 0);
          }
        }
        float pr[4];
#pragma unroll
        for (int r = 0; r < 4; ++r) {
          float a2 = 0.f;
#pragma unroll
          for (int nt = 0; nt < 5; ++nt) a2 = fmaf(fmaxf(acc[nt][r], 0.f), w2l[nt], a2);
          pr[r] = a2;
        }
#pragma unroll
        for (int r = 0; r < 4; ++r) {
          pr[r] += __shfl_xor(pr[r], 1);
          pr[r] += __shfl_xor(pr[r], 2);
          pr[r] += __shfl_xor(pr[r], 4);
          pr[r] += __shfl_xor(pr[r], 8);
        }
        if ((lane & 15) == 0) {
          int srow2 = wave * 16 + (lane >> 4) * 4;
#pragma unroll
          for (int r = 0; r < 4; ++r) {
            int kk = g0 + srow2 + r;
            if (kk < c) out[sOrig[kk]] = pr[r] + b2 + dlacc;
          }
        }
      }
    }
    __syncthreads();   // volley k+2 staged AND consumers done with buf k%3
  }
}

extern "C" void kernel_launch(void* const* d_in, const int* in_sizes, int n_in,
                              void* d_out, int out_size, void* d_ws, size_t ws_size,
                              hipStream_t stream) {
  const int*   pid      = (const int*)d_in[0];
  const int*   feats    = (const int*)d_in[1];
  const float* emb_pid  = (const float*)d_in[2];
  const float* emb_f    = (const float*)d_in[3];
  const float* sw1      = (const float*)d_in[4];
  const float* dw1      = (const float*)d_in[5];
  const float* sb1      = (const float*)d_in[6];
  const float* db1      = (const float*)d_in[7];
  const float* sw2      = (const float*)d_in[8];
  const float* dw2      = (const float*)d_in[9];
  const float* sb2      = (const float*)d_in[10];
  const float* db2      = (const float*)d_in[11];
  const float* dl_w     = (const float*)d_in[12];
  const float* dl_b     = (const float*)d_in[13];
  float* out = (float*)d_out;
  (void)d_ws; (void)ws_size;

  k_main<<<NWND * ND, 512, 0, stream>>>(pid, feats, emb_pid, emb_f, sw1, dw1,
                                        sb1, db1, sw2, dw2, sb2, db2, dl_w,
                                        dl_b, out);
}